// Round 12
// baseline (245.691 us; speedup 1.0000x reference)
//
#include <hip/hip_runtime.h>
#include <stdint.h>

#define NTOK   8192
#define DIM    1024
#define NEXP   8
#define MAXP   8192

typedef float        f32x4  __attribute__((ext_vector_type(4)));
typedef unsigned int u32x4  __attribute__((ext_vector_type(4)));
typedef __bf16       bf16x8 __attribute__((ext_vector_type(8)));
typedef _Float16     h16x8  __attribute__((ext_vector_type(8)));

typedef __attribute__((address_space(1))) const void* gas_ptr;
typedef __attribute__((address_space(3))) void*       las_ptr;

__device__ __forceinline__ unsigned short f32_to_bf16(float f) {
  union { float f; unsigned int u; } v; v.f = f;
  unsigned int u = v.u;
  unsigned int r = (u + 0x7FFFu + ((u >> 16) & 1u)) >> 16;
  return (unsigned short)r;
}

// ---------------------------------------------------------------------------
// Weight prep: We[e][d][h] fp32 -> Wf bf16 TILE-LINEAR (unchanged from R10).
// ---------------------------------------------------------------------------
__global__ __launch_bounds__(256) void wprep_kernel(
    const float* __restrict__ We, unsigned short* __restrict__ Wf) {
  __shared__ float tile[64][65];
  const int bid = blockIdx.x;
  const int e  = bid >> 8;
  const int d0 = ((bid >> 4) & 15) * 64;
  const int h0 = (bid & 15) * 64;
  const int t  = threadIdx.x;
  const float* src = We + (size_t)e * DIM * DIM;
  const int rr = t >> 4;            // 0..15
  const int cc = (t & 15) * 4;      // 0..60
#pragma unroll
  for (int p = 0; p < 4; ++p) {
    const int row = rr + p * 16;
    f32x4 v = *(const f32x4*)(src + (size_t)(d0 + row) * DIM + (h0 + cc));
    tile[row][cc]     = v[0];
    tile[row][cc + 1] = v[1];
    tile[row][cc + 2] = v[2];
    tile[row][cc + 3] = v[3];
  }
  __syncthreads();
  const int nt    = h0 >> 7;
  const int rbase = h0 & 64;
  const int hl    = t >> 2;
  const int k8    = t & 3;
#pragma unroll
  for (int reg = 0; reg < 2; ++reg) {
    const int kt = (d0 >> 5) + reg;
    unsigned int pk[4];
#pragma unroll
    for (int q = 0; q < 4; ++q) {
      int dl = reg * 32 + k8 * 8 + q * 2;
      pk[q] = (unsigned int)f32_to_bf16(tile[dl][hl]) |
              ((unsigned int)f32_to_bf16(tile[dl + 1][hl]) << 16);
    }
    size_t base = (((size_t)(e * 8 + nt) * 32 + kt) << 12) +
                  (size_t)(rbase + hl) * 32 + k8 * 8;
    u32x4 w = {pk[0], pk[1], pk[2], pk[3]};
    *(u32x4*)&Wf[base] = w;
  }
}

// ---------------------------------------------------------------------------
// Gate prep (unchanged from R10). NO global atomics (R6 lesson).
// ---------------------------------------------------------------------------
__global__ __launch_bounds__(256) void gate_kernel(
    const float* __restrict__ x, const float* __restrict__ Wg,
    const float* __restrict__ bg, unsigned short* __restrict__ Xbf,
    int* __restrict__ tok_ee, float2* __restrict__ tok_w) {
  const int wave = threadIdx.x >> 6;
  const int lane = threadIdx.x & 63;
  const int tok0 = blockIdx.x * 16 + wave * 4;

  float xs[4][16];
#pragma unroll
  for (int t = 0; t < 4; ++t) {
    const float* xr = x + (size_t)(tok0 + t) * DIM + lane * 16;
#pragma unroll
    for (int i = 0; i < 4; ++i)
      *(f32x4*)&xs[t][i * 4] = *(const f32x4*)(xr + i * 4);
  }
#pragma unroll
  for (int t = 0; t < 4; ++t) {
    unsigned int pk[8];
#pragma unroll
    for (int i = 0; i < 8; ++i)
      pk[i] = (unsigned int)f32_to_bf16(xs[t][2 * i]) |
              ((unsigned int)f32_to_bf16(xs[t][2 * i + 1]) << 16);
    u32x4* xb = (u32x4*)(Xbf + (size_t)(tok0 + t) * DIM + lane * 16);
    u32x4 w0 = {pk[0], pk[1], pk[2], pk[3]};
    u32x4 w1 = {pk[4], pk[5], pk[6], pk[7]};
    xb[0] = w0;
    xb[1] = w1;
  }

  double acc[4][8];
#pragma unroll
  for (int t = 0; t < 4; ++t)
#pragma unroll
    for (int e = 0; e < 8; ++e) acc[t][e] = 0.0;

  const float* wr = Wg + (size_t)(lane * 16) * NEXP;
#pragma unroll
  for (int i = 0; i < 16; ++i) {
    f32x4 wa = *(const f32x4*)(wr + i * 8);
    f32x4 wb = *(const f32x4*)(wr + i * 8 + 4);
    double w0 = wa[0], w1 = wa[1], w2 = wa[2], w3 = wa[3];
    double w4 = wb[0], w5 = wb[1], w6 = wb[2], w7 = wb[3];
#pragma unroll
    for (int t = 0; t < 4; ++t) {
      double xd = (double)xs[t][i];
      acc[t][0] += xd * w0; acc[t][1] += xd * w1;
      acc[t][2] += xd * w2; acc[t][3] += xd * w3;
      acc[t][4] += xd * w4; acc[t][5] += xd * w5;
      acc[t][6] += xd * w6; acc[t][7] += xd * w7;
    }
  }
#pragma unroll
  for (int m = 1; m < 64; m <<= 1)
#pragma unroll
    for (int t = 0; t < 4; ++t)
#pragma unroll
      for (int e = 0; e < 8; ++e) acc[t][e] += __shfl_xor(acc[t][e], m, 64);

  if (lane == 0) {
#pragma unroll
    for (int t = 0; t < 4; ++t) {
      float s[8];
#pragma unroll
      for (int e = 0; e < 8; ++e) s[e] = (float)acc[t][e] + bg[e];
      int i0 = 0; float v0 = s[0];
#pragma unroll
      for (int e = 1; e < 8; ++e) if (s[e] > v0) { v0 = s[e]; i0 = e; }
      int i1 = -1; float v1 = -3.4e38f;
#pragma unroll
      for (int e = 0; e < 8; ++e) if (e != i0 && s[e] > v1) { v1 = s[e]; i1 = e; }
      float t1 = expf(v1 - v0);
      float den = 1.0f + t1;
      tok_ee[tok0 + t] = i0 | (i1 << 8);
      tok_w[tok0 + t]  = make_float2(1.0f / den, t1 / den);
    }
  }
}

// ---------------------------------------------------------------------------
// Parallel deterministic compaction (unchanged, R1-proven).
// ---------------------------------------------------------------------------
__global__ __launch_bounds__(1024) void compact_kernel(
    const int* __restrict__ tok_ee, const float2* __restrict__ tok_w,
    int* __restrict__ counts, int* __restrict__ pair_token,
    float* __restrict__ pair_w) {
  __shared__ int wave_cnt[16];
  __shared__ int wave_off[16];
  const int e = blockIdx.x;
  const int tid = threadIdx.x, wave = tid >> 6, lane = tid & 63;
  int base = 0;
  for (int c = 0; c < NTOK / 1024; ++c) {
    const int t = c * 1024 + tid;
    const int p = tok_ee[t];
    const bool m0 = ((p & 255) == e);
    const bool m1 = (((p >> 8) & 255) == e);
    const unsigned long long m = __ballot(m0 || m1);
    const int pre = __popcll(m & ((1ull << lane) - 1ull));
    if (lane == 0) wave_cnt[wave] = __popcll(m);
    __syncthreads();
    if (tid == 0) {
      int s = base;
      for (int w = 0; w < 16; ++w) { wave_off[w] = s; s += wave_cnt[w]; }
      base = s;
    }
    __syncthreads();
    if (m0 || m1) {
      const float2 w = tok_w[t];
      const int slot = wave_off[wave] + pre;
      pair_token[e * MAXP + slot] = (t << 1) | (m1 ? 1 : 0);
      pair_w[e * MAXP + slot]     = m1 ? w.y : w.x;
    }
    __syncthreads();
  }
  if (tid == 0) counts[e] = base;
}

// ---------------------------------------------------------------------------
// A-gather (R11 fix: u32x4 ext_vector for nontemporal stores) — materialize
// slot-compacted A in Wf's TILE-LINEAR layout:
//   Ap offset(e,mt,kt,r128,k8) = ((e*32+mt)*32 + kt)<<12 | r128*32+k8*8.
// Moves the token-row scatter OUT of the gemm k-loop; both global sides are
// contiguous 1KB per wave-inst. Invalid (pad) rows zeroed.
// Covers mt<32 (cnt<=4096, ~31 sigma); gemm falls back beyond.
// Grid: 8e x 8group x 32mt = 2048 blocks; block = 16 rows.
// ---------------------------------------------------------------------------
__global__ __launch_bounds__(256) void gather_kernel(
    const unsigned short* __restrict__ Xbf, const int* __restrict__ counts,
    const int* __restrict__ pair_token, unsigned short* __restrict__ Ap) {
  __shared__ __align__(16) unsigned short rows[16][1040];   // +16 elem pad
  const int bid = blockIdx.x;
  const int e  = bid & 7;
  const int g  = (bid >> 3) & 7;
  const int mt = bid >> 6;                    // 0..31
  const int cnt = counts[e];
  const int m0g = mt * 128 + g * 16;
  if (m0g >= ((cnt + 127) & ~127)) return;    // whole 16-row group dead
  const int wave = threadIdx.x >> 6, lane = threadIdx.x & 63;
  // ---- load: 4 rows per wave, 2x 1KB coalesced reads each; zero pad rows --
#pragma unroll
  for (int q = 0; q < 4; ++q) {
    const int r    = wave * 4 + q;
    const int slot = m0g + r;
    u32x4 v0 = {0u, 0u, 0u, 0u}, v1 = {0u, 0u, 0u, 0u};
    if (slot < cnt) {
      const int tok = pair_token[e * MAXP + slot] >> 1;
      const u32x4* src = (const u32x4*)(Xbf + (size_t)tok * DIM + lane * 8);
      v0 = src[0];
      v1 = src[64];                           // +512 elems
    }
    *(u32x4*)&rows[r][lane * 8]       = v0;
    *(u32x4*)&rows[r][lane * 8 + 512] = v1;
  }
  __syncthreads();
  // ---- store: per kt, 16 rows x 64B = contiguous 1KB; 8 kt per wave ------
  const int r  = lane >> 2;
  const int k8 = lane & 3;
  unsigned short* dst0 = Ap + (((size_t)(e * 32 + mt) * 32) << 12) +
                         (size_t)(g * 16 + r) * 32 + k8 * 8;
#pragma unroll
  for (int q = 0; q < 8; ++q) {
    const int kt = wave * 8 + q;
    u32x4 v = *(const u32x4*)&rows[r][kt * 32 + k8 * 8];
    __builtin_nontemporal_store(v, (u32x4*)(dst0 + ((size_t)kt << 12)));
  }
}

// ---------------------------------------------------------------------------
// Grouped GEMM — R7/R10 structure (BM=128, BN=256, BK=32, 3-buf, vmcnt(3),
// chunk-swizzle) with ONE change: when use_ap, A stages from the tile-linear
// Ap buffer (contiguous 1KB, astep=128 — identical pattern to B) instead of
// the scattered token-row gather (astep=1). Fallback preserves R10 exactly.
// ---------------------------------------------------------------------------
__global__ __launch_bounds__(512, 4) void moe_gemm(
    const unsigned short* __restrict__ Xbf, const unsigned short* __restrict__ Wf,
    const unsigned short* __restrict__ Ap, const float* __restrict__ be,
    const int* __restrict__ counts, const int* __restrict__ pair_token,
    const float* __restrict__ pair_w, _Float16* __restrict__ part,
    float* __restrict__ Y, int use_part, int use_ap) {
  const int id    = blockIdx.x;
  const int e     = id & 7;                 // expert -> XCD affinity
  const int ntile = (id >> 3) & 3;          // 256-col tile
  const int m0    = (id >> 5) * 128;        // m-tile 0..63
  const int cnt   = counts[e];
  if (m0 >= cnt) return;

  __shared__ __align__(16) unsigned short As[3][128 * 32];  // 8 KB / buf
  __shared__ __align__(16) unsigned short Bs[3][256 * 32];  // 16 KB / buf

  const int tid  = threadIdx.x;
  const int wave = tid >> 6;                // 0..7
  const int lane = tid & 63;
  const int fm   = lane & 15;
  const int fq   = lane >> 4;
  const int wm   = wave >> 2;               // 0..1 (M half)
  const int wn   = wave & 3;                // 0..3 (N quarter)

  // staging source chunk swizzle (R1-proven, 0 conflicts)
  const int kc = (((lane & 3) ^ ((lane >> 3) & 3)) * 8);
  // A source: tile-linear Ap (1KB contiguous) or scattered token rows.
  const unsigned short* gA;
  size_t astep;
  if (use_ap && m0 < 4096) {
    gA = Ap + (((size_t)(e * 32 + (m0 >> 7)) * 32) << 12) +
         (size_t)(wave * 16 + (lane >> 2)) * 32 + kc;
    astep = 128;                            // kt<<12 == k0*128
  } else {
    const int grA = m0 + wave * 16 + (lane >> 2);
    const int tkA = (grA < cnt) ? (pair_token[e * MAXP + grA] >> 1) : 0;
    gA = Xbf + (size_t)tkA * DIM + kc;
    astep = 1;
  }
  // B: wave stages 16-row groups 2w, 2w+1 of the 256-row B tile
  const unsigned short* gB[2];
#pragma unroll
  for (int l = 0; l < 2; ++l) {
    const int R16 = wave * 2 + l;             // 0..15
    const int cg  = ntile * 2 + (R16 >> 3);   // Wf 128-col group 0..7
    gB[l] = Wf + ((size_t)(e * 8 + cg) << 17) +
            (size_t)((R16 & 7) * 16 + (lane >> 2)) * 32 + kc;
  }

#define STAGE(buf, k0v)                                                       \
  {                                                                           \
    __builtin_amdgcn_global_load_lds(                                         \
        (gas_ptr)(uintptr_t)(gA + (size_t)(k0v) * astep),                     \
        (las_ptr)(uintptr_t)(&As[buf][wave * 512]), 16, 0, 0);                \
    _Pragma("unroll") for (int l = 0; l < 2; ++l)                             \
      __builtin_amdgcn_global_load_lds(                                       \
          (gas_ptr)(uintptr_t)(gB[l] + (size_t)(k0v) * 128),                  \
          (las_ptr)(uintptr_t)(&Bs[buf][(wave * 2 + l) * 512]), 16, 0, 0);    \
  }

  f32x4 acc[4][4];
#pragma unroll
  for (int i = 0; i < 4; ++i)
#pragma unroll
    for (int j = 0; j < 4; ++j) { f32x4 z = {0.f, 0.f, 0.f, 0.f}; acc[i][j] = z; }

  // swizzled ds_read chunk; row bases (row*32 elems, 64B rows)
  const int rdo  = (fq ^ ((fm >> 1) & 3)) * 8;
  const int arow = (wm * 64 + fm) * 32 + rdo;     // + i*512
  const int brow = (wn * 64 + fm) * 32 + rdo;     // + j*512

  STAGE(0, 0);
  STAGE(1, 32);
  int cur = 0;
  for (int k0 = 0; k0 < DIM; k0 += 32) {
    asm volatile("s_waitcnt vmcnt(3)" ::: "memory");   // buf[cur] resident
    __builtin_amdgcn_s_barrier();

    int kn = k0 + 64;
    if (kn >= DIM) kn = 0;                   // dummy re-stage keeps count exact
    int nb = cur + 2;
    if (nb >= 3) nb -= 3;
    STAGE(nb, kn);

    bf16x8 af[4], bfr[4];
#pragma unroll
    for (int i = 0; i < 4; ++i)
      af[i] = *(const bf16x8*)&As[cur][arow + i * 512];
#pragma unroll
    for (int j = 0; j < 4; ++j)
      bfr[j] = *(const bf16x8*)&Bs[cur][brow + j * 512];
#pragma unroll
    for (int i = 0; i < 4; ++i)
#pragma unroll
      for (int j = 0; j < 4; ++j)
        acc[i][j] = __builtin_amdgcn_mfma_f32_16x16x32_bf16(af[i], bfr[j],
                                                            acc[i][j], 0, 0, 0);
    cur = (cur + 1 == 3) ? 0 : cur + 1;
  }
  asm volatile("s_waitcnt vmcnt(0)" ::: "memory");     // drain dummy stages
#undef STAGE

  // ---- epilogue (per-i pair loads to limit register pressure) ----
#pragma unroll
  for (int i = 0; i < 4; ++i) {
    int   rv[4];
    float wv[4];
#pragma unroll
    for (int r = 0; r < 4; ++r) {
      int gr = m0 + wm * 64 + i * 16 + fq * 4 + r;
      bool valid = gr < cnt;
      rv[r] = valid ? pair_token[e * MAXP + gr] : -1;
      wv[r] = valid ? pair_w[e * MAXP + gr] : 0.f;
    }
    if (use_part) {
#pragma unroll
      for (int j = 0; j < 4; ++j) {
        int col = ntile * 256 + wn * 64 + j * 16 + fm;
        float bev = be[e * DIM + col];
#pragma unroll
        for (int r = 0; r < 4; ++r) {
          int v = rv[r];
          if (v >= 0)
            __builtin_nontemporal_store(
                (_Float16)(wv[r] * (acc[i][j][r] + bev)),
                &part[(size_t)v * DIM + col]);
        }
      }
    } else {
#pragma unroll
      for (int j = 0; j < 4; ++j) {
        int col = ntile * 256 + wn * 64 + j * 16 + fm;
        float bev = be[e * DIM + col];
#pragma unroll
        for (int r = 0; r < 4; ++r) {
          int v = rv[r];
          if (v >= 0)
            atomicAdd(Y + (size_t)(v >> 1) * DIM + col,
                      wv[r] * (acc[i][j][r] + bev));
        }
      }
    }
  }
}

// ---------------------------------------------------------------------------
// Y[t][d] = part[2t][d] + part[2t+1][d]; fp16 in, fp32 out (unchanged).
// ---------------------------------------------------------------------------
__global__ __launch_bounds__(256) void reduce_pairs(
    const _Float16* __restrict__ part, float* __restrict__ Y) {
  const int g = blockIdx.x * 256 + threadIdx.x;
  const int t = g >> 7;
  const int o = (g & 127) * 8;
  const h16x8 a =
      __builtin_nontemporal_load((const h16x8*)(part + (size_t)(2 * t) * DIM + o));
  const h16x8 b =
      __builtin_nontemporal_load((const h16x8*)(part + (size_t)(2 * t + 1) * DIM + o));
  float* y = Y + (size_t)t * DIM + o;
  f32x4 lo = {(float)a[0] + (float)b[0], (float)a[1] + (float)b[1],
              (float)a[2] + (float)b[2], (float)a[3] + (float)b[3]};
  f32x4 hi = {(float)a[4] + (float)b[4], (float)a[5] + (float)b[5],
              (float)a[6] + (float)b[6], (float)a[7] + (float)b[7]};
  __builtin_nontemporal_store(lo, (f32x4*)y);
  __builtin_nontemporal_store(hi, (f32x4*)(y + 4));
}

// ---------------------------------------------------------------------------
extern "C" void kernel_launch(void* const* d_in, const int* in_sizes, int n_in,
                              void* d_out, int out_size, void* d_ws, size_t ws_size,
                              hipStream_t stream) {
  const float* x  = (const float*)d_in[0];
  const float* Wg = (const float*)d_in[1];
  const float* bg = (const float*)d_in[2];
  const float* We = (const float*)d_in[3];
  const float* be = (const float*)d_in[4];
  float* Y = (float*)d_out;

  const size_t MB = 1024 * 1024;
  char* ws = (char*)d_ws;
  unsigned short* Xbf = (unsigned short*)ws;                 // 16 MiB @ 0
  unsigned short* Wf  = (unsigned short*)(ws + 16 * MB);     // 16 MiB @ 16
  const size_t part_bytes = (size_t)NTOK * 2 * DIM * 2;      // 32 MiB (fp16)
  const size_t need_old = 32 * MB + part_bytes + 1 * MB;     // 65 MiB
  const size_t ap_bytes = (size_t)8 * 32 * 32 * 4096 * 2;    // 64 MiB (Ap)
  const size_t need_ap  = 32 * MB + ap_bytes + part_bytes + 1 * MB;  // 129 MiB
  const int use_ap   = ws_size >= need_ap;
  const int use_part = ws_size >= need_old;

  unsigned short* Aprime = (unsigned short*)(ws + 32 * MB);  // 64 MiB @ 32
  _Float16* part;
  char* p2;
  if (use_ap) {
    part = (_Float16*)(ws + 96 * MB);
    p2   = ws + 96 * MB + part_bytes;
  } else {
    part = (_Float16*)(ws + 32 * MB);
    p2   = ws + 32 * MB + (use_part ? part_bytes : 0);
  }
  int*    counts     = (int*)p2;
  int*    pair_token = (int*)(p2 + 256);
  float*  pair_w     = (float*)(p2 + 256 + 262144);
  int*    tok_ee     = (int*)(p2 + 256 + 2 * 262144);
  float2* tok_w      = (float2*)(p2 + 256 + 2 * 262144 + 32768);

  if (!use_part)
    (void)hipMemsetAsync(d_out, 0, (size_t)out_size * sizeof(float), stream);

  wprep_kernel<<<2048, 256, 0, stream>>>(We, Wf);
  gate_kernel<<<512, 256, 0, stream>>>(x, Wg, bg, Xbf, tok_ee, tok_w);
  compact_kernel<<<NEXP, 1024, 0, stream>>>(tok_ee, tok_w, counts, pair_token,
                                            pair_w);
  if (use_ap)
    gather_kernel<<<2048, 256, 0, stream>>>(Xbf, counts, pair_token, Aprime);
  moe_gemm<<<8 * 4 * (MAXP / 128), 512, 0, stream>>>(
      Xbf, Wf, Aprime, be, counts, pair_token, pair_w, part, Y, use_part,
      use_ap);
  if (use_part)
    reduce_pairs<<<NTOK * DIM / 8 / 256, 256, 0, stream>>>(part, Y);
}

// Round 13
// 209.211 us; speedup vs baseline: 1.1744x; 1.1744x over previous
//
#include <hip/hip_runtime.h>
#include <stdint.h>

#define NTOK   8192
#define DIM    1024
#define NEXP   8
#define MAXP   8192

typedef float        f32x4  __attribute__((ext_vector_type(4)));
typedef unsigned int u32x4  __attribute__((ext_vector_type(4)));
typedef __bf16       bf16x8 __attribute__((ext_vector_type(8)));
typedef _Float16     h16x8  __attribute__((ext_vector_type(8)));

typedef __attribute__((address_space(1))) const void* gas_ptr;
typedef __attribute__((address_space(3))) void*       las_ptr;

__device__ __forceinline__ unsigned short f32_to_bf16(float f) {
  union { float f; unsigned int u; } v; v.f = f;
  unsigned int u = v.u;
  unsigned int r = (u + 0x7FFFu + ((u >> 16) & 1u)) >> 16;
  return (unsigned short)r;
}

// ---------------------------------------------------------------------------
// Weight prep: We[e][d][h] fp32 -> Wf bf16 TILE-LINEAR (unchanged).
// ---------------------------------------------------------------------------
__global__ __launch_bounds__(256) void wprep_kernel(
    const float* __restrict__ We, unsigned short* __restrict__ Wf) {
  __shared__ float tile[64][65];
  const int bid = blockIdx.x;
  const int e  = bid >> 8;
  const int d0 = ((bid >> 4) & 15) * 64;
  const int h0 = (bid & 15) * 64;
  const int t  = threadIdx.x;
  const float* src = We + (size_t)e * DIM * DIM;
  const int rr = t >> 4;            // 0..15
  const int cc = (t & 15) * 4;      // 0..60
#pragma unroll
  for (int p = 0; p < 4; ++p) {
    const int row = rr + p * 16;
    f32x4 v = *(const f32x4*)(src + (size_t)(d0 + row) * DIM + (h0 + cc));
    tile[row][cc]     = v[0];
    tile[row][cc + 1] = v[1];
    tile[row][cc + 2] = v[2];
    tile[row][cc + 3] = v[3];
  }
  __syncthreads();
  const int nt    = h0 >> 7;
  const int rbase = h0 & 64;
  const int hl    = t >> 2;
  const int k8    = t & 3;
#pragma unroll
  for (int reg = 0; reg < 2; ++reg) {
    const int kt = (d0 >> 5) + reg;
    unsigned int pk[4];
#pragma unroll
    for (int q = 0; q < 4; ++q) {
      int dl = reg * 32 + k8 * 8 + q * 2;
      pk[q] = (unsigned int)f32_to_bf16(tile[dl][hl]) |
              ((unsigned int)f32_to_bf16(tile[dl + 1][hl]) << 16);
    }
    size_t base = (((size_t)(e * 8 + nt) * 32 + kt) << 12) +
                  (size_t)(rbase + hl) * 32 + k8 * 8;
    u32x4 w = {pk[0], pk[1], pk[2], pk[3]};
    *(u32x4*)&Wf[base] = w;
  }
}

// ---------------------------------------------------------------------------
// Gate prep (unchanged). NO global atomics (R6 lesson).
// ---------------------------------------------------------------------------
__global__ __launch_bounds__(256) void gate_kernel(
    const float* __restrict__ x, const float* __restrict__ Wg,
    const float* __restrict__ bg, unsigned short* __restrict__ Xbf,
    int* __restrict__ tok_ee, float2* __restrict__ tok_w) {
  const int wave = threadIdx.x >> 6;
  const int lane = threadIdx.x & 63;
  const int tok0 = blockIdx.x * 16 + wave * 4;

  float xs[4][16];
#pragma unroll
  for (int t = 0; t < 4; ++t) {
    const float* xr = x + (size_t)(tok0 + t) * DIM + lane * 16;
#pragma unroll
    for (int i = 0; i < 4; ++i)
      *(f32x4*)&xs[t][i * 4] = *(const f32x4*)(xr + i * 4);
  }
#pragma unroll
  for (int t = 0; t < 4; ++t) {
    unsigned int pk[8];
#pragma unroll
    for (int i = 0; i < 8; ++i)
      pk[i] = (unsigned int)f32_to_bf16(xs[t][2 * i]) |
              ((unsigned int)f32_to_bf16(xs[t][2 * i + 1]) << 16);
    u32x4* xb = (u32x4*)(Xbf + (size_t)(tok0 + t) * DIM + lane * 16);
    u32x4 w0 = {pk[0], pk[1], pk[2], pk[3]};
    u32x4 w1 = {pk[4], pk[5], pk[6], pk[7]};
    xb[0] = w0;
    xb[1] = w1;
  }

  double acc[4][8];
#pragma unroll
  for (int t = 0; t < 4; ++t)
#pragma unroll
    for (int e = 0; e < 8; ++e) acc[t][e] = 0.0;

  const float* wr = Wg + (size_t)(lane * 16) * NEXP;
#pragma unroll
  for (int i = 0; i < 16; ++i) {
    f32x4 wa = *(const f32x4*)(wr + i * 8);
    f32x4 wb = *(const f32x4*)(wr + i * 8 + 4);
    double w0 = wa[0], w1 = wa[1], w2 = wa[2], w3 = wa[3];
    double w4 = wb[0], w5 = wb[1], w6 = wb[2], w7 = wb[3];
#pragma unroll
    for (int t = 0; t < 4; ++t) {
      double xd = (double)xs[t][i];
      acc[t][0] += xd * w0; acc[t][1] += xd * w1;
      acc[t][2] += xd * w2; acc[t][3] += xd * w3;
      acc[t][4] += xd * w4; acc[t][5] += xd * w5;
      acc[t][6] += xd * w6; acc[t][7] += xd * w7;
    }
  }
#pragma unroll
  for (int m = 1; m < 64; m <<= 1)
#pragma unroll
    for (int t = 0; t < 4; ++t)
#pragma unroll
      for (int e = 0; e < 8; ++e) acc[t][e] += __shfl_xor(acc[t][e], m, 64);

  if (lane == 0) {
#pragma unroll
    for (int t = 0; t < 4; ++t) {
      float s[8];
#pragma unroll
      for (int e = 0; e < 8; ++e) s[e] = (float)acc[t][e] + bg[e];
      int i0 = 0; float v0 = s[0];
#pragma unroll
      for (int e = 1; e < 8; ++e) if (s[e] > v0) { v0 = s[e]; i0 = e; }
      int i1 = -1; float v1 = -3.4e38f;
#pragma unroll
      for (int e = 0; e < 8; ++e) if (e != i0 && s[e] > v1) { v1 = s[e]; i1 = e; }
      float t1 = expf(v1 - v0);
      float den = 1.0f + t1;
      tok_ee[tok0 + t] = i0 | (i1 << 8);
      tok_w[tok0 + t]  = make_float2(1.0f / den, t1 / den);
    }
  }
}

// ---------------------------------------------------------------------------
// Parallel deterministic compaction (unchanged, R1-proven).
// ---------------------------------------------------------------------------
__global__ __launch_bounds__(1024) void compact_kernel(
    const int* __restrict__ tok_ee, const float2* __restrict__ tok_w,
    int* __restrict__ counts, int* __restrict__ pair_token,
    float* __restrict__ pair_w) {
  __shared__ int wave_cnt[16];
  __shared__ int wave_off[16];
  const int e = blockIdx.x;
  const int tid = threadIdx.x, wave = tid >> 6, lane = tid & 63;
  int base = 0;
  for (int c = 0; c < NTOK / 1024; ++c) {
    const int t = c * 1024 + tid;
    const int p = tok_ee[t];
    const bool m0 = ((p & 255) == e);
    const bool m1 = (((p >> 8) & 255) == e);
    const unsigned long long m = __ballot(m0 || m1);
    const int pre = __popcll(m & ((1ull << lane) - 1ull));
    if (lane == 0) wave_cnt[wave] = __popcll(m);
    __syncthreads();
    if (tid == 0) {
      int s = base;
      for (int w = 0; w < 16; ++w) { wave_off[w] = s; s += wave_cnt[w]; }
      base = s;
    }
    __syncthreads();
    if (m0 || m1) {
      const float2 w = tok_w[t];
      const int slot = wave_off[wave] + pre;
      pair_token[e * MAXP + slot] = (t << 1) | (m1 ? 1 : 0);
      pair_w[e * MAXP + slot]     = m1 ? w.y : w.x;
    }
    __syncthreads();
  }
  if (tid == 0) counts[e] = base;
}

// ---------------------------------------------------------------------------
// Grouped GEMM — R13: BM=160 (was 128) kills the XCD spill round.
// Spill analysis (R12 post-mortem): e=id&7 pins expert->XCD (64 block slots
// at 2 blocks/CU x 32 CUs). cnt_e ~ 2048+-42 -> ceil(cnt/128)=17 m-tiles for
// ~half the experts -> 68 blocks > 64 slots -> a 4-block second round while
// 480 slots idle => wall ~ 2x T_block (the stuck ~80us and MfmaUtil ~17%).
// BM=160: ceil(cnt/160) <= 16 tiles for cnt <= 2560 (12 sigma) -> <=56 blocks
// per XCD -> guaranteed single round. LDS 3x(10+16)KB = 78KB -> 2 blocks/CU.
// A staging = 10x 16-row units/step: every wave stages unit w; waves 0,1 also
// stage units 8,9 -> per-wave counted vmcnt(4) (w<2) / vmcnt(3) (w>=2).
// Register diet for the (512,4) bound: acc[5][4] + single sequential af.
// Schedule/swizzle otherwise identical to the proven R10 kernel.
// cnt > 2560 (p~1e-33) handled by outer m-loop (+2560).
// ---------------------------------------------------------------------------
__global__ __launch_bounds__(512, 4) void moe_gemm(
    const unsigned short* __restrict__ Xbf, const unsigned short* __restrict__ Wf,
    const float* __restrict__ be, const int* __restrict__ counts,
    const int* __restrict__ pair_token, const float* __restrict__ pair_w,
    _Float16* __restrict__ part, float* __restrict__ Y, int use_part) {
  const int id    = blockIdx.x;
  const int e     = id & 7;                 // expert -> XCD affinity
  const int ntile = (id >> 3) & 3;          // 256-col tile
  const int mt    = id >> 5;                // m-tile 0..15
  const int cnt   = counts[e];

  __shared__ __align__(16) unsigned short As[3][160 * 32];  // 10 KB / buf
  __shared__ __align__(16) unsigned short Bs[3][256 * 32];  // 16 KB / buf

  const int tid  = threadIdx.x;
  const int wave = tid >> 6;                // 0..7
  const int lane = tid & 63;
  const int fm   = lane & 15;
  const int fq   = lane >> 4;
  const int wm   = wave >> 2;               // 0..1 (M half, 80 rows each)
  const int wn   = wave & 3;                // 0..3 (N quarter)

  // staging source chunk swizzle (R1-proven, 0 conflicts)
  const int kc = (((lane & 3) ^ ((lane >> 3) & 3)) * 8);
  // B: wave stages 16-row groups 2w, 2w+1 of the 256-row B tile (unchanged)
  const unsigned short* gB[2];
#pragma unroll
  for (int l = 0; l < 2; ++l) {
    const int R16 = wave * 2 + l;             // 0..15
    const int cg  = ntile * 2 + (R16 >> 3);   // Wf 128-col group 0..7
    gB[l] = Wf + ((size_t)(e * 8 + cg) << 17) +
            (size_t)((R16 & 7) * 16 + (lane >> 2)) * 32 + kc;
  }

  // swizzled ds_read chunk; row bases (row*32 elems, 64B rows)
  const int rdo  = (fq ^ ((fm >> 1) & 3)) * 8;
  const int arow = (wm * 80 + fm) * 32 + rdo;     // + i*512, i<5
  const int brow = (wn * 64 + fm) * 32 + rdo;     // + j*512

  for (int m0 = mt * 160; m0 < cnt; m0 += 2560) {
    __syncthreads();                        // LDS safe across outer iterations

    // A: unit w (all waves) + units 8,9 (waves 0,1)
    const int grA0 = m0 + wave * 16 + (lane >> 2);
    const int tk0  = (grA0 < cnt) ? (pair_token[e * MAXP + grA0] >> 1) : 0;
    const unsigned short* gA0 = Xbf + (size_t)tk0 * DIM + kc;
    const int grA1 = m0 + 128 + wave * 16 + (lane >> 2);   // waves 0,1 only
    const int tk1  = (grA1 < cnt) ? (pair_token[e * MAXP + grA1] >> 1) : 0;
    const unsigned short* gA1 = Xbf + (size_t)tk1 * DIM + kc;

#define STAGE(buf, k0v)                                                       \
  {                                                                           \
    __builtin_amdgcn_global_load_lds(                                         \
        (gas_ptr)(uintptr_t)(gA0 + (k0v)),                                    \
        (las_ptr)(uintptr_t)(&As[buf][wave * 512]), 16, 0, 0);                \
    if (wave < 2)                                                             \
      __builtin_amdgcn_global_load_lds(                                       \
          (gas_ptr)(uintptr_t)(gA1 + (k0v)),                                  \
          (las_ptr)(uintptr_t)(&As[buf][(8 + wave) * 512]), 16, 0, 0);        \
    _Pragma("unroll") for (int l = 0; l < 2; ++l)                             \
      __builtin_amdgcn_global_load_lds(                                       \
          (gas_ptr)(uintptr_t)(gB[l] + (size_t)(k0v) * 128),                  \
          (las_ptr)(uintptr_t)(&Bs[buf][(wave * 2 + l) * 512]), 16, 0, 0);    \
  }

    f32x4 acc[5][4];
#pragma unroll
    for (int i = 0; i < 5; ++i)
#pragma unroll
      for (int j = 0; j < 4; ++j) { f32x4 z = {0.f, 0.f, 0.f, 0.f}; acc[i][j] = z; }

    STAGE(0, 0);
    STAGE(1, 32);
    int cur = 0;
    for (int k0 = 0; k0 < DIM; k0 += 32) {
      // retire oldest stage-group (per-wave load count differs: 4 vs 3)
      if (wave < 2) { asm volatile("s_waitcnt vmcnt(4)" ::: "memory"); }
      else          { asm volatile("s_waitcnt vmcnt(3)" ::: "memory"); }
      __builtin_amdgcn_s_barrier();

      int kn = k0 + 64;
      if (kn >= DIM) kn = 0;                 // dummy re-stage keeps count exact
      int nb = cur + 2;
      if (nb >= 3) nb -= 3;
      STAGE(nb, kn);

      bf16x8 bfr[4];
#pragma unroll
      for (int j = 0; j < 4; ++j)
        bfr[j] = *(const bf16x8*)&Bs[cur][brow + j * 512];
#pragma unroll
      for (int i = 0; i < 5; ++i) {
        bf16x8 af = *(const bf16x8*)&As[cur][arow + i * 512];
#pragma unroll
        for (int j = 0; j < 4; ++j)
          acc[i][j] = __builtin_amdgcn_mfma_f32_16x16x32_bf16(af, bfr[j],
                                                              acc[i][j], 0, 0, 0);
      }
      cur = (cur + 1 == 3) ? 0 : cur + 1;
    }
    asm volatile("s_waitcnt vmcnt(0)" ::: "memory");     // drain dummy stages
#undef STAGE

    // ---- epilogue (per-i pair loads to limit register pressure) ----
#pragma unroll
    for (int i = 0; i < 5; ++i) {
      int   rv[4];
      float wv[4];
#pragma unroll
      for (int r = 0; r < 4; ++r) {
        int gr = m0 + wm * 80 + i * 16 + fq * 4 + r;
        bool valid = gr < cnt;
        rv[r] = valid ? pair_token[e * MAXP + gr] : -1;
        wv[r] = valid ? pair_w[e * MAXP + gr] : 0.f;
      }
      if (use_part) {
#pragma unroll
        for (int j = 0; j < 4; ++j) {
          int col = ntile * 256 + wn * 64 + j * 16 + fm;
          float bev = be[e * DIM + col];
#pragma unroll
          for (int r = 0; r < 4; ++r) {
            int v = rv[r];
            if (v >= 0)
              __builtin_nontemporal_store(
                  (_Float16)(wv[r] * (acc[i][j][r] + bev)),
                  &part[(size_t)v * DIM + col]);
          }
        }
      } else {
#pragma unroll
        for (int j = 0; j < 4; ++j) {
          int col = ntile * 256 + wn * 64 + j * 16 + fm;
          float bev = be[e * DIM + col];
#pragma unroll
          for (int r = 0; r < 4; ++r) {
            int v = rv[r];
            if (v >= 0)
              atomicAdd(Y + (size_t)(v >> 1) * DIM + col,
                        wv[r] * (acc[i][j][r] + bev));
          }
        }
      }
    }
  }
}

// ---------------------------------------------------------------------------
// Y[t][d] = part[2t][d] + part[2t+1][d]; fp16 in, fp32 out (unchanged).
// ---------------------------------------------------------------------------
__global__ __launch_bounds__(256) void reduce_pairs(
    const _Float16* __restrict__ part, float* __restrict__ Y) {
  const int g = blockIdx.x * 256 + threadIdx.x;
  const int t = g >> 7;
  const int o = (g & 127) * 8;
  const h16x8 a =
      __builtin_nontemporal_load((const h16x8*)(part + (size_t)(2 * t) * DIM + o));
  const h16x8 b =
      __builtin_nontemporal_load((const h16x8*)(part + (size_t)(2 * t + 1) * DIM + o));
  float* y = Y + (size_t)t * DIM + o;
  f32x4 lo = {(float)a[0] + (float)b[0], (float)a[1] + (float)b[1],
              (float)a[2] + (float)b[2], (float)a[3] + (float)b[3]};
  f32x4 hi = {(float)a[4] + (float)b[4], (float)a[5] + (float)b[5],
              (float)a[6] + (float)b[6], (float)a[7] + (float)b[7]};
  __builtin_nontemporal_store(lo, (f32x4*)y);
  __builtin_nontemporal_store(hi, (f32x4*)(y + 4));
}

// ---------------------------------------------------------------------------
extern "C" void kernel_launch(void* const* d_in, const int* in_sizes, int n_in,
                              void* d_out, int out_size, void* d_ws, size_t ws_size,
                              hipStream_t stream) {
  const float* x  = (const float*)d_in[0];
  const float* Wg = (const float*)d_in[1];
  const float* bg = (const float*)d_in[2];
  const float* We = (const float*)d_in[3];
  const float* be = (const float*)d_in[4];
  float* Y = (float*)d_out;

  const size_t MB = 1024 * 1024;
  char* ws = (char*)d_ws;
  unsigned short* Xbf = (unsigned short*)ws;                 // 16 MiB
  unsigned short* Wf  = (unsigned short*)(ws + 16 * MB);     // 16 MiB
  const size_t part_bytes = (size_t)NTOK * 2 * DIM * 2;      // 32 MiB (fp16)
  const size_t need = 32 * MB + part_bytes + 1 * MB;
  const int use_part = ws_size >= need;
  _Float16* part = (_Float16*)(ws + 32 * MB);
  char* p2 = ws + 32 * MB + (use_part ? part_bytes : 0);
  int*    counts     = (int*)p2;
  int*    pair_token = (int*)(p2 + 256);
  float*  pair_w     = (float*)(p2 + 256 + 262144);
  int*    tok_ee     = (int*)(p2 + 256 + 2 * 262144);
  float2* tok_w      = (float2*)(p2 + 256 + 2 * 262144 + 32768);

  if (!use_part)
    (void)hipMemsetAsync(d_out, 0, (size_t)out_size * sizeof(float), stream);

  wprep_kernel<<<2048, 256, 0, stream>>>(We, Wf);
  gate_kernel<<<512, 256, 0, stream>>>(x, Wg, bg, Xbf, tok_ee, tok_w);
  compact_kernel<<<NEXP, 1024, 0, stream>>>(tok_ee, tok_w, counts, pair_token,
                                            pair_w);
  moe_gemm<<<8 * 4 * 16, 512, 0, stream>>>(
      Xbf, Wf, be, counts, pair_token, pair_w, part, Y, use_part);
  if (use_part)
    reduce_pairs<<<NTOK * DIM / 8 / 256, 256, 0, stream>>>(part, Y);
}

// Round 14
// 207.619 us; speedup vs baseline: 1.1834x; 1.0077x over previous
//
#include <hip/hip_runtime.h>
#include <stdint.h>

#define NTOK   8192
#define DIM    1024
#define NEXP   8
#define MAXP   8192

typedef float        f32x4  __attribute__((ext_vector_type(4)));
typedef unsigned int u32x4  __attribute__((ext_vector_type(4)));
typedef __bf16       bf16x8 __attribute__((ext_vector_type(8)));
typedef _Float16     h16x8  __attribute__((ext_vector_type(8)));

typedef __attribute__((address_space(1))) const void* gas_ptr;
typedef __attribute__((address_space(3))) void*       las_ptr;

__device__ __forceinline__ unsigned short f32_to_bf16(float f) {
  union { float f; unsigned int u; } v; v.f = f;
  unsigned int u = v.u;
  unsigned int r = (u + 0x7FFFu + ((u >> 16) & 1u)) >> 16;
  return (unsigned short)r;
}

// ---------------------------------------------------------------------------
// Weight prep: We[e][d][h] fp32 -> Wf bf16 TILE-LINEAR (unchanged).
// ---------------------------------------------------------------------------
__global__ __launch_bounds__(256) void wprep_kernel(
    const float* __restrict__ We, unsigned short* __restrict__ Wf) {
  __shared__ float tile[64][65];
  const int bid = blockIdx.x;
  const int e  = bid >> 8;
  const int d0 = ((bid >> 4) & 15) * 64;
  const int h0 = (bid & 15) * 64;
  const int t  = threadIdx.x;
  const float* src = We + (size_t)e * DIM * DIM;
  const int rr = t >> 4;            // 0..15
  const int cc = (t & 15) * 4;      // 0..60
#pragma unroll
  for (int p = 0; p < 4; ++p) {
    const int row = rr + p * 16;
    f32x4 v = *(const f32x4*)(src + (size_t)(d0 + row) * DIM + (h0 + cc));
    tile[row][cc]     = v[0];
    tile[row][cc + 1] = v[1];
    tile[row][cc + 2] = v[2];
    tile[row][cc + 3] = v[3];
  }
  __syncthreads();
  const int nt    = h0 >> 7;
  const int rbase = h0 & 64;
  const int hl    = t >> 2;
  const int k8    = t & 3;
#pragma unroll
  for (int reg = 0; reg < 2; ++reg) {
    const int kt = (d0 >> 5) + reg;
    unsigned int pk[4];
#pragma unroll
    for (int q = 0; q < 4; ++q) {
      int dl = reg * 32 + k8 * 8 + q * 2;
      pk[q] = (unsigned int)f32_to_bf16(tile[dl][hl]) |
              ((unsigned int)f32_to_bf16(tile[dl + 1][hl]) << 16);
    }
    size_t base = (((size_t)(e * 8 + nt) * 32 + kt) << 12) +
                  (size_t)(rbase + hl) * 32 + k8 * 8;
    u32x4 w = {pk[0], pk[1], pk[2], pk[3]};
    *(u32x4*)&Wf[base] = w;
  }
}

// ---------------------------------------------------------------------------
// Gate prep (unchanged). NO global atomics (R6 lesson).
// ---------------------------------------------------------------------------
__global__ __launch_bounds__(256) void gate_kernel(
    const float* __restrict__ x, const float* __restrict__ Wg,
    const float* __restrict__ bg, unsigned short* __restrict__ Xbf,
    int* __restrict__ tok_ee, float2* __restrict__ tok_w) {
  const int wave = threadIdx.x >> 6;
  const int lane = threadIdx.x & 63;
  const int tok0 = blockIdx.x * 16 + wave * 4;

  float xs[4][16];
#pragma unroll
  for (int t = 0; t < 4; ++t) {
    const float* xr = x + (size_t)(tok0 + t) * DIM + lane * 16;
#pragma unroll
    for (int i = 0; i < 4; ++i)
      *(f32x4*)&xs[t][i * 4] = *(const f32x4*)(xr + i * 4);
  }
#pragma unroll
  for (int t = 0; t < 4; ++t) {
    unsigned int pk[8];
#pragma unroll
    for (int i = 0; i < 8; ++i)
      pk[i] = (unsigned int)f32_to_bf16(xs[t][2 * i]) |
              ((unsigned int)f32_to_bf16(xs[t][2 * i + 1]) << 16);
    u32x4* xb = (u32x4*)(Xbf + (size_t)(tok0 + t) * DIM + lane * 16);
    u32x4 w0 = {pk[0], pk[1], pk[2], pk[3]};
    u32x4 w1 = {pk[4], pk[5], pk[6], pk[7]};
    xb[0] = w0;
    xb[1] = w1;
  }

  double acc[4][8];
#pragma unroll
  for (int t = 0; t < 4; ++t)
#pragma unroll
    for (int e = 0; e < 8; ++e) acc[t][e] = 0.0;

  const float* wr = Wg + (size_t)(lane * 16) * NEXP;
#pragma unroll
  for (int i = 0; i < 16; ++i) {
    f32x4 wa = *(const f32x4*)(wr + i * 8);
    f32x4 wb = *(const f32x4*)(wr + i * 8 + 4);
    double w0 = wa[0], w1 = wa[1], w2 = wa[2], w3 = wa[3];
    double w4 = wb[0], w5 = wb[1], w6 = wb[2], w7 = wb[3];
#pragma unroll
    for (int t = 0; t < 4; ++t) {
      double xd = (double)xs[t][i];
      acc[t][0] += xd * w0; acc[t][1] += xd * w1;
      acc[t][2] += xd * w2; acc[t][3] += xd * w3;
      acc[t][4] += xd * w4; acc[t][5] += xd * w5;
      acc[t][6] += xd * w6; acc[t][7] += xd * w7;
    }
  }
#pragma unroll
  for (int m = 1; m < 64; m <<= 1)
#pragma unroll
    for (int t = 0; t < 4; ++t)
#pragma unroll
      for (int e = 0; e < 8; ++e) acc[t][e] += __shfl_xor(acc[t][e], m, 64);

  if (lane == 0) {
#pragma unroll
    for (int t = 0; t < 4; ++t) {
      float s[8];
#pragma unroll
      for (int e = 0; e < 8; ++e) s[e] = (float)acc[t][e] + bg[e];
      int i0 = 0; float v0 = s[0];
#pragma unroll
      for (int e = 1; e < 8; ++e) if (s[e] > v0) { v0 = s[e]; i0 = e; }
      int i1 = -1; float v1 = -3.4e38f;
#pragma unroll
      for (int e = 0; e < 8; ++e) if (e != i0 && s[e] > v1) { v1 = s[e]; i1 = e; }
      float t1 = expf(v1 - v0);
      float den = 1.0f + t1;
      tok_ee[tok0 + t] = i0 | (i1 << 8);
      tok_w[tok0 + t]  = make_float2(1.0f / den, t1 / den);
    }
  }
}

// ---------------------------------------------------------------------------
// Parallel deterministic compaction — R14 rewrite (same outputs, bitwise):
// old: 8 sequential chunk loads + 24 barriers + 8x16 serial tid0 LDS scan
//      (~20-30us latency chain on 8 blocks).
// new: all 8 chunk loads issued upfront (overlapped); ballots into
//      wave_cnt[8][16]; ONE wave-parallel 128-element exclusive prefix scan
//      (6 shfl_up steps, 2 vals/lane, order i=c*16+w == lane order); one
//      write pass. 2 barriers total. Slot order identical: ascending
//      (chunk, wave, lane) = ascending token.
// ---------------------------------------------------------------------------
__global__ __launch_bounds__(1024) void compact_kernel(
    const int* __restrict__ tok_ee, const float2* __restrict__ tok_w,
    int* __restrict__ counts, int* __restrict__ pair_token,
    float* __restrict__ pair_w) {
  __shared__ int wave_cnt[8][16];
  __shared__ int wave_off[8][16];
  const int e = blockIdx.x;
  const int tid = threadIdx.x, wave = tid >> 6, lane = tid & 63;

  int pre[8];
  unsigned int mmAny = 0, mm1 = 0;
#pragma unroll
  for (int c = 0; c < 8; ++c) {
    const int p = tok_ee[c * 1024 + tid];          // 8 independent loads
    const bool b0 = ((p & 255) == e);
    const bool b1 = (((p >> 8) & 255) == e);
    mmAny |= (unsigned)(b0 || b1) << c;
    mm1   |= (unsigned)b1 << c;
    const unsigned long long mk = __ballot(b0 || b1);
    pre[c] = __popcll(mk & ((1ull << lane) - 1ull));
    if (lane == 0) wave_cnt[c][wave] = __popcll(mk);
  }
  __syncthreads();

  if (wave == 0) {
    const int c0 = lane >> 4, w0 = lane & 15;      // i = c0*16+w0 = lane
    int v0 = wave_cnt[c0][w0];                     // chunks 0..3
    int v1 = wave_cnt[4 + c0][w0];                 // chunks 4..7
    int s0 = v0, s1 = v1;
#pragma unroll
    for (int d = 1; d < 64; d <<= 1) {
      int t0 = __shfl_up(s0, d, 64);
      int t1 = __shfl_up(s1, d, 64);
      if (lane >= d) { s0 += t0; s1 += t1; }
    }
    const int tot0 = __shfl(s0, 63, 64);           // total of chunks 0..3
    wave_off[c0][w0]     = s0 - v0;                // exclusive prefix
    wave_off[4 + c0][w0] = s1 - v1 + tot0;
    if (lane == 63) counts[e] = tot0 + s1;         // grand total
  }
  __syncthreads();

#pragma unroll
  for (int c = 0; c < 8; ++c) {
    if ((mmAny >> c) & 1u) {
      const int t = c * 1024 + tid;
      const float2 w = tok_w[t];
      const bool b1 = (mm1 >> c) & 1u;
      const int slot = wave_off[c][wave] + pre[c];
      pair_token[e * MAXP + slot] = (t << 1) | (b1 ? 1 : 0);
      pair_w[e * MAXP + slot]     = b1 ? w.y : w.x;
    }
  }
}

// ---------------------------------------------------------------------------
// Grouped GEMM — FROZEN at R13 config (best measured: 66 us, single round).
// BM=160, BN=256, BK=32, 8 waves, 3-buf, per-wave counted vmcnt, swizzle.
// ---------------------------------------------------------------------------
__global__ __launch_bounds__(512, 4) void moe_gemm(
    const unsigned short* __restrict__ Xbf, const unsigned short* __restrict__ Wf,
    const float* __restrict__ be, const int* __restrict__ counts,
    const int* __restrict__ pair_token, const float* __restrict__ pair_w,
    _Float16* __restrict__ part, float* __restrict__ Y, int use_part) {
  const int id    = blockIdx.x;
  const int e     = id & 7;                 // expert -> XCD affinity
  const int ntile = (id >> 3) & 3;          // 256-col tile
  const int mt    = id >> 5;                // m-tile 0..15
  const int cnt   = counts[e];

  __shared__ __align__(16) unsigned short As[3][160 * 32];  // 10 KB / buf
  __shared__ __align__(16) unsigned short Bs[3][256 * 32];  // 16 KB / buf

  const int tid  = threadIdx.x;
  const int wave = tid >> 6;                // 0..7
  const int lane = tid & 63;
  const int fm   = lane & 15;
  const int fq   = lane >> 4;
  const int wm   = wave >> 2;               // 0..1 (M half, 80 rows each)
  const int wn   = wave & 3;                // 0..3 (N quarter)

  // staging source chunk swizzle (R1-proven, 0 conflicts)
  const int kc = (((lane & 3) ^ ((lane >> 3) & 3)) * 8);
  // B: wave stages 16-row groups 2w, 2w+1 of the 256-row B tile
  const unsigned short* gB[2];
#pragma unroll
  for (int l = 0; l < 2; ++l) {
    const int R16 = wave * 2 + l;             // 0..15
    const int cg  = ntile * 2 + (R16 >> 3);   // Wf 128-col group 0..7
    gB[l] = Wf + ((size_t)(e * 8 + cg) << 17) +
            (size_t)((R16 & 7) * 16 + (lane >> 2)) * 32 + kc;
  }

  // swizzled ds_read chunk; row bases (row*32 elems, 64B rows)
  const int rdo  = (fq ^ ((fm >> 1) & 3)) * 8;
  const int arow = (wm * 80 + fm) * 32 + rdo;     // + i*512, i<5
  const int brow = (wn * 64 + fm) * 32 + rdo;     // + j*512

  for (int m0 = mt * 160; m0 < cnt; m0 += 2560) {
    __syncthreads();                        // LDS safe across outer iterations

    // A: unit w (all waves) + units 8,9 (waves 0,1)
    const int grA0 = m0 + wave * 16 + (lane >> 2);
    const int tk0  = (grA0 < cnt) ? (pair_token[e * MAXP + grA0] >> 1) : 0;
    const unsigned short* gA0 = Xbf + (size_t)tk0 * DIM + kc;
    const int grA1 = m0 + 128 + wave * 16 + (lane >> 2);   // waves 0,1 only
    const int tk1  = (grA1 < cnt) ? (pair_token[e * MAXP + grA1] >> 1) : 0;
    const unsigned short* gA1 = Xbf + (size_t)tk1 * DIM + kc;

#define STAGE(buf, k0v)                                                       \
  {                                                                           \
    __builtin_amdgcn_global_load_lds(                                         \
        (gas_ptr)(uintptr_t)(gA0 + (k0v)),                                    \
        (las_ptr)(uintptr_t)(&As[buf][wave * 512]), 16, 0, 0);                \
    if (wave < 2)                                                             \
      __builtin_amdgcn_global_load_lds(                                       \
          (gas_ptr)(uintptr_t)(gA1 + (k0v)),                                  \
          (las_ptr)(uintptr_t)(&As[buf][(8 + wave) * 512]), 16, 0, 0);        \
    _Pragma("unroll") for (int l = 0; l < 2; ++l)                             \
      __builtin_amdgcn_global_load_lds(                                       \
          (gas_ptr)(uintptr_t)(gB[l] + (size_t)(k0v) * 128),                  \
          (las_ptr)(uintptr_t)(&Bs[buf][(wave * 2 + l) * 512]), 16, 0, 0);    \
  }

    f32x4 acc[5][4];
#pragma unroll
    for (int i = 0; i < 5; ++i)
#pragma unroll
      for (int j = 0; j < 4; ++j) { f32x4 z = {0.f, 0.f, 0.f, 0.f}; acc[i][j] = z; }

    STAGE(0, 0);
    STAGE(1, 32);
    int cur = 0;
    for (int k0 = 0; k0 < DIM; k0 += 32) {
      // retire oldest stage-group (per-wave load count differs: 4 vs 3)
      if (wave < 2) { asm volatile("s_waitcnt vmcnt(4)" ::: "memory"); }
      else          { asm volatile("s_waitcnt vmcnt(3)" ::: "memory"); }
      __builtin_amdgcn_s_barrier();

      int kn = k0 + 64;
      if (kn >= DIM) kn = 0;                 // dummy re-stage keeps count exact
      int nb = cur + 2;
      if (nb >= 3) nb -= 3;
      STAGE(nb, kn);

      bf16x8 bfr[4];
#pragma unroll
      for (int j = 0; j < 4; ++j)
        bfr[j] = *(const bf16x8*)&Bs[cur][brow + j * 512];
#pragma unroll
      for (int i = 0; i < 5; ++i) {
        bf16x8 af = *(const bf16x8*)&As[cur][arow + i * 512];
#pragma unroll
        for (int j = 0; j < 4; ++j)
          acc[i][j] = __builtin_amdgcn_mfma_f32_16x16x32_bf16(af, bfr[j],
                                                              acc[i][j], 0, 0, 0);
      }
      cur = (cur + 1 == 3) ? 0 : cur + 1;
    }
    asm volatile("s_waitcnt vmcnt(0)" ::: "memory");     // drain dummy stages
#undef STAGE

    // ---- epilogue (per-i pair loads to limit register pressure) ----
#pragma unroll
    for (int i = 0; i < 5; ++i) {
      int   rv[4];
      float wv[4];
#pragma unroll
      for (int r = 0; r < 4; ++r) {
        int gr = m0 + wm * 80 + i * 16 + fq * 4 + r;
        bool valid = gr < cnt;
        rv[r] = valid ? pair_token[e * MAXP + gr] : -1;
        wv[r] = valid ? pair_w[e * MAXP + gr] : 0.f;
      }
      if (use_part) {
#pragma unroll
        for (int j = 0; j < 4; ++j) {
          int col = ntile * 256 + wn * 64 + j * 16 + fm;
          float bev = be[e * DIM + col];
#pragma unroll
          for (int r = 0; r < 4; ++r) {
            int v = rv[r];
            if (v >= 0)
              __builtin_nontemporal_store(
                  (_Float16)(wv[r] * (acc[i][j][r] + bev)),
                  &part[(size_t)v * DIM + col]);
          }
        }
      } else {
#pragma unroll
        for (int j = 0; j < 4; ++j) {
          int col = ntile * 256 + wn * 64 + j * 16 + fm;
          float bev = be[e * DIM + col];
#pragma unroll
          for (int r = 0; r < 4; ++r) {
            int v = rv[r];
            if (v >= 0)
              atomicAdd(Y + (size_t)(v >> 1) * DIM + col,
                        wv[r] * (acc[i][j][r] + bev));
          }
        }
      }
    }
  }
}

// ---------------------------------------------------------------------------
// Y[t][d] = part[2t][d] + part[2t+1][d]; fp16 in, fp32 out (unchanged).
// ---------------------------------------------------------------------------
__global__ __launch_bounds__(256) void reduce_pairs(
    const _Float16* __restrict__ part, float* __restrict__ Y) {
  const int g = blockIdx.x * 256 + threadIdx.x;
  const int t = g >> 7;
  const int o = (g & 127) * 8;
  const h16x8 a =
      __builtin_nontemporal_load((const h16x8*)(part + (size_t)(2 * t) * DIM + o));
  const h16x8 b =
      __builtin_nontemporal_load((const h16x8*)(part + (size_t)(2 * t + 1) * DIM + o));
  float* y = Y + (size_t)t * DIM + o;
  f32x4 lo = {(float)a[0] + (float)b[0], (float)a[1] + (float)b[1],
              (float)a[2] + (float)b[2], (float)a[3] + (float)b[3]};
  f32x4 hi = {(float)a[4] + (float)b[4], (float)a[5] + (float)b[5],
              (float)a[6] + (float)b[6], (float)a[7] + (float)b[7]};
  __builtin_nontemporal_store(lo, (f32x4*)y);
  __builtin_nontemporal_store(hi, (f32x4*)(y + 4));
}

// ---------------------------------------------------------------------------
extern "C" void kernel_launch(void* const* d_in, const int* in_sizes, int n_in,
                              void* d_out, int out_size, void* d_ws, size_t ws_size,
                              hipStream_t stream) {
  const float* x  = (const float*)d_in[0];
  const float* Wg = (const float*)d_in[1];
  const float* bg = (const float*)d_in[2];
  const float* We = (const float*)d_in[3];
  const float* be = (const float*)d_in[4];
  float* Y = (float*)d_out;

  const size_t MB = 1024 * 1024;
  char* ws = (char*)d_ws;
  unsigned short* Xbf = (unsigned short*)ws;                 // 16 MiB
  unsigned short* Wf  = (unsigned short*)(ws + 16 * MB);     // 16 MiB
  const size_t part_bytes = (size_t)NTOK * 2 * DIM * 2;      // 32 MiB (fp16)
  const size_t need = 32 * MB + part_bytes + 1 * MB;
  const int use_part = ws_size >= need;
  _Float16* part = (_Float16*)(ws + 32 * MB);
  char* p2 = ws + 32 * MB + (use_part ? part_bytes : 0);
  int*    counts     = (int*)p2;
  int*    pair_token = (int*)(p2 + 256);
  float*  pair_w     = (float*)(p2 + 256 + 262144);
  int*    tok_ee     = (int*)(p2 + 256 + 2 * 262144);
  float2* tok_w      = (float2*)(p2 + 256 + 2 * 262144 + 32768);

  if (!use_part)
    (void)hipMemsetAsync(d_out, 0, (size_t)out_size * sizeof(float), stream);

  wprep_kernel<<<2048, 256, 0, stream>>>(We, Wf);
  gate_kernel<<<512, 256, 0, stream>>>(x, Wg, bg, Xbf, tok_ee, tok_w);
  compact_kernel<<<NEXP, 1024, 0, stream>>>(tok_ee, tok_w, counts, pair_token,
                                            pair_w);
  moe_gemm<<<8 * 4 * 16, 512, 0, stream>>>(
      Xbf, Wf, be, counts, pair_token, pair_w, part, Y, use_part);
  if (use_part)
    reduce_pairs<<<NTOK * DIM / 8 / 256, 256, 0, stream>>>(part, Y);
}